// Round 1
// baseline (38.290 us; speedup 1.0000x reference)
//
#include <hip/hip_runtime.h>
#include <hip/hip_bf16.h>

#define H 1024
#define MAXLEN 512

// ---------------- K0: gather embed row + build cat = [embed | hidden], and cat2 embed half
__global__ void k0_gather(const int* __restrict__ inputId,
                          const float* __restrict__ embed_table,
                          const float* __restrict__ hidden,
                          float* __restrict__ ws) {
    int t = blockIdx.x * blockDim.x + threadIdx.x; // 0..2047
    int id = inputId[0];
    if (t < H) {
        float e = embed_table[(size_t)id * H + t];
        ws[t] = e;            // cat[0..1023]   (embed)
        ws[4096 + t] = e;     // cat2[0..1023]  (embed)
    } else if (t < 2 * H) {
        ws[t] = hidden[t - H];  // cat[1024..2047] (hidden)
    }
}

__device__ __forceinline__ float wave_reduce(float a) {
    #pragma unroll
    for (int off = 32; off; off >>= 1) a += __shfl_xor(a, off);
    return a;
}

// ---------------- K1: logits[row] = attn_w[row,:] . cat + attn_b[row]   (512 rows x 2048)
__global__ void k1_logits(const float* __restrict__ attn_w,
                          const float* __restrict__ attn_b,
                          const float* __restrict__ cat,
                          float* __restrict__ logits) {
    int lane = threadIdx.x & 63;
    int row = blockIdx.x * 4 + (threadIdx.x >> 6); // 0..511
    const float* wrow = attn_w + (size_t)row * (2 * H);
    float acc = 0.f;
    #pragma unroll
    for (int it = 0; it < 8; ++it) {
        int base = it * 256 + lane * 4;
        float4 wv = *reinterpret_cast<const float4*>(wrow + base);
        float4 cv = *reinterpret_cast<const float4*>(cat + base);
        acc += wv.x * cv.x + wv.y * cv.y + wv.z * cv.z + wv.w * cv.w;
    }
    acc = wave_reduce(acc);
    if (lane == 0) logits[row] = acc + attn_b[row];
}

// ---------------- K2: softmax over 512 logits -> weights (ws) + attnWeights (d_out)
__global__ void k2_softmax(const float* __restrict__ logits,
                           float* __restrict__ weights,
                           float* __restrict__ out_w) {
    __shared__ float sm[MAXLEN];
    int t = threadIdx.x;
    float l = logits[t];
    sm[t] = l;
    __syncthreads();
    for (int s = 256; s; s >>= 1) {
        if (t < s) sm[t] = fmaxf(sm[t], sm[t + s]);
        __syncthreads();
    }
    float m = sm[0];
    __syncthreads();
    float e = expf(l - m);
    sm[t] = e;
    __syncthreads();
    for (int s = 256; s; s >>= 1) {
        if (t < s) sm[t] += sm[t + s];
        __syncthreads();
    }
    float w = e / sm[0];
    weights[t] = w;
    out_w[t] = w;
}

// ---------------- K3: attnApplied[j] = sum_k weights[k] * enc[k][j]   (1024 outs, 512 k)
__global__ void k3_apply(const float* __restrict__ enc,
                         const float* __restrict__ weights,
                         float* __restrict__ attnApplied) {
    int j2 = (blockIdx.x * blockDim.x + threadIdx.x) * 2; // 0..1022
    float a0 = 0.f, a1 = 0.f;
    for (int k = 0; k < MAXLEN; ++k) {
        float w = weights[k];
        float2 ev = *reinterpret_cast<const float2*>(enc + (size_t)k * H + j2);
        a0 += w * ev.x;
        a1 += w * ev.y;
    }
    attnApplied[j2] = a0;
    attnApplied[j2 + 1] = a1;
}

// ---------------- K4: x[row] = relu(comb_w[row,:] . cat2 + comb_b[row])  (1024 rows x 2048)
__global__ void k4_combine(const float* __restrict__ comb_w,
                           const float* __restrict__ comb_b,
                           const float* __restrict__ cat2,
                           float* __restrict__ x) {
    int lane = threadIdx.x & 63;
    int row = blockIdx.x * 4 + (threadIdx.x >> 6); // 0..1023
    const float* wrow = comb_w + (size_t)row * (2 * H);
    float acc = 0.f;
    #pragma unroll
    for (int it = 0; it < 8; ++it) {
        int base = it * 256 + lane * 4;
        float4 wv = *reinterpret_cast<const float4*>(wrow + base);
        float4 cv = *reinterpret_cast<const float4*>(cat2 + base);
        acc += wv.x * cv.x + wv.y * cv.y + wv.z * cv.z + wv.w * cv.w;
    }
    acc = wave_reduce(acc);
    if (lane == 0) x[row] = fmaxf(acc + comb_b[row], 0.f);
}

// ---------------- K5: GRU step (h0 = 0 -> gh = b_hh).  wave per output j, 3 dots of 1024.
__global__ void k5_gru(const float* __restrict__ w_ih,
                       const float* __restrict__ b_ih,
                       const float* __restrict__ b_hh,
                       const float* __restrict__ x,
                       float* __restrict__ d_out) {
    int lane = threadIdx.x & 63;
    int j = blockIdx.x * 4 + (threadIdx.x >> 6); // 0..1023
    float acc0 = 0.f, acc1 = 0.f, acc2 = 0.f;
    const float* wr = w_ih + (size_t)j * H;
    const float* wz = w_ih + (size_t)(H + j) * H;
    const float* wn = w_ih + (size_t)(2 * H + j) * H;
    #pragma unroll
    for (int it = 0; it < 4; ++it) {
        int base = it * 256 + lane * 4;
        float4 xv = *reinterpret_cast<const float4*>(x + base);
        float4 a = *reinterpret_cast<const float4*>(wr + base);
        float4 b = *reinterpret_cast<const float4*>(wz + base);
        float4 c = *reinterpret_cast<const float4*>(wn + base);
        acc0 += a.x * xv.x + a.y * xv.y + a.z * xv.z + a.w * xv.w;
        acc1 += b.x * xv.x + b.y * xv.y + b.z * xv.z + b.w * xv.w;
        acc2 += c.x * xv.x + c.y * xv.y + c.z * xv.z + c.w * xv.w;
    }
    #pragma unroll
    for (int off = 32; off; off >>= 1) {
        acc0 += __shfl_xor(acc0, off);
        acc1 += __shfl_xor(acc1, off);
        acc2 += __shfl_xor(acc2, off);
    }
    if (lane == 0) {
        float gi_r = acc0 + b_ih[j];
        float gi_z = acc1 + b_ih[H + j];
        float gi_n = acc2 + b_ih[2 * H + j];
        float h_r = b_hh[j], h_z = b_hh[H + j], h_n = b_hh[2 * H + j];
        float r = 1.f / (1.f + expf(-(gi_r + h_r)));
        float z = 1.f / (1.f + expf(-(gi_z + h_z)));
        float n = tanhf(gi_n + r * h_n);
        float hnew = (1.f - z) * n;           // + z*h0, h0 = 0
        float outv = 1.f / (1.f + expf(-hnew));
        d_out[j] = outv;        // out
        d_out[H + j] = hnew;    // h_new
    }
}

extern "C" void kernel_launch(void* const* d_in, const int* in_sizes, int n_in,
                              void* d_out, int out_size, void* d_ws, size_t ws_size,
                              hipStream_t stream) {
    const int*   inputId     = (const int*)d_in[0];
    const float* hidden      = (const float*)d_in[1];
    const float* enc         = (const float*)d_in[2];
    const float* embed_table = (const float*)d_in[3];
    const float* attn_w      = (const float*)d_in[4];
    const float* attn_b      = (const float*)d_in[5];
    const float* comb_w      = (const float*)d_in[6];
    const float* comb_b      = (const float*)d_in[7];
    const float* w_ih        = (const float*)d_in[8];
    // d_in[9] = w_hh is dead: h0 == 0 so gh = b_hh
    const float* b_ih        = (const float*)d_in[10];
    const float* b_hh        = (const float*)d_in[11];

    float* out = (float*)d_out;   // [0:1024) out, [1024:2048) h_new, [2048:2560) attnWeights
    float* ws  = (float*)d_ws;

    float* cat         = ws;            // 2048 floats: [embed | hidden]
    float* logits      = ws + 2048;     // 512
    float* weights     = ws + 2560;     // 512
    float* cat2        = ws + 4096;     // 2048 floats: [embed | attnApplied]
    float* attnApplied = ws + 5120;     // (= cat2 + 1024)
    float* x           = ws + 6144;     // 1024

    k0_gather <<<8,   256, 0, stream>>>(inputId, embed_table, hidden, ws);
    k1_logits <<<128, 256, 0, stream>>>(attn_w, attn_b, cat, logits);
    k2_softmax<<<1,   512, 0, stream>>>(logits, weights, out + 2048);
    k3_apply  <<<2,   256, 0, stream>>>(enc, weights, attnApplied);
    k4_combine<<<256, 256, 0, stream>>>(comb_w, comb_b, cat2, x);
    k5_gru    <<<256, 256, 0, stream>>>(w_ih, b_ih, b_hh, x, out);
}

// Round 2
// 24.323 us; speedup vs baseline: 1.5742x; 1.5742x over previous
//
#include <hip/hip_runtime.h>
#include <hip/hip_bf16.h>

#define H 1024
#define MAXLEN 512

__device__ __forceinline__ float wave_reduce_sum(float a) {
    #pragma unroll
    for (int off = 32; off; off >>= 1) a += __shfl_xor(a, off);
    return a;
}
__device__ __forceinline__ float wave_reduce_max(float a) {
    #pragma unroll
    for (int off = 32; off; off >>= 1) a = fmaxf(a, __shfl_xor(a, off));
    return a;
}

// ---------------- A: logits[row] = attn_w[row,:] . [embed|hidden] + attn_b[row]
// 512 rows x 2048. Gather fused: embed row + hidden read directly (L2-resident).
__global__ void kA_logits(const int* __restrict__ inputId,
                          const float* __restrict__ embed_table,
                          const float* __restrict__ hidden,
                          const float* __restrict__ attn_w,
                          const float* __restrict__ attn_b,
                          float* __restrict__ logits) {
    int lane = threadIdx.x & 63;
    int row = blockIdx.x * 4 + (threadIdx.x >> 6); // 0..511
    const float* embed = embed_table + (size_t)inputId[0] * H;
    const float* wrow = attn_w + (size_t)row * (2 * H);
    float acc = 0.f;
    #pragma unroll
    for (int it = 0; it < 8; ++it) {
        int base = it * 256 + lane * 4;
        float4 wv = *reinterpret_cast<const float4*>(wrow + base);
        float4 cv = (it < 4)
            ? *reinterpret_cast<const float4*>(embed + base)
            : *reinterpret_cast<const float4*>(hidden + (base - H));
        acc += wv.x * cv.x + wv.y * cv.y + wv.z * cv.z + wv.w * cv.w;
    }
    acc = wave_reduce_sum(acc);
    if (lane == 0) logits[row] = acc + attn_b[row];
}

// ---------------- B: softmax(512) [redundant per block] + attnApplied = w @ enc
// 32 blocks x 256 threads; block b owns columns [b*32, b*32+32).
__global__ void kB_softmax_apply(const float* __restrict__ logits,
                                 const float* __restrict__ enc,
                                 float* __restrict__ attnApplied,
                                 float* __restrict__ out_w) {
    __shared__ float w_lds[MAXLEN];
    __shared__ float red[4];
    __shared__ float part[8][32];
    int tid = threadIdx.x;          // 0..255
    int lane = tid & 63, wid = tid >> 6;

    float l0 = logits[tid];
    float l1 = logits[tid + 256];

    // block max (2 barriers)
    float m = wave_reduce_max(fmaxf(l0, l1));
    if (lane == 0) red[wid] = m;
    __syncthreads();
    m = fmaxf(fmaxf(red[0], red[1]), fmaxf(red[2], red[3]));
    __syncthreads();

    float e0 = expf(l0 - m), e1 = expf(l1 - m);

    // block sum (2 barriers)
    float s = wave_reduce_sum(e0 + e1);
    if (lane == 0) red[wid] = s;
    __syncthreads();
    s = red[0] + red[1] + red[2] + red[3];
    float inv = 1.f / s;

    float w0 = e0 * inv, w1 = e1 * inv;
    w_lds[tid] = w0;
    w_lds[tid + 256] = w1;
    if (blockIdx.x == 0) {          // attnWeights output (one block only)
        out_w[tid] = w0;
        out_w[tid + 256] = w1;
    }
    __syncthreads();

    // apply: this block's 32 columns, all 512 k
    int c = tid & 31;               // column within stripe
    int ks = tid >> 5;              // k-slice 0..7
    int col = blockIdx.x * 32 + c;
    float acc = 0.f;
    for (int k = ks; k < MAXLEN; k += 8)
        acc += w_lds[k] * enc[(size_t)k * H + col];
    part[ks][c] = acc;
    __syncthreads();
    if (tid < 32) {
        float t = 0.f;
        #pragma unroll
        for (int i = 0; i < 8; ++i) t += part[i][tid];
        attnApplied[blockIdx.x * 32 + tid] = t;
    }
}

// ---------------- C: x[row] = relu(comb_w[row,:] . [embed|attnApplied] + comb_b[row])
__global__ void kC_combine(const int* __restrict__ inputId,
                           const float* __restrict__ embed_table,
                           const float* __restrict__ attnApplied,
                           const float* __restrict__ comb_w,
                           const float* __restrict__ comb_b,
                           float* __restrict__ x) {
    int lane = threadIdx.x & 63;
    int row = blockIdx.x * 4 + (threadIdx.x >> 6); // 0..1023
    const float* embed = embed_table + (size_t)inputId[0] * H;
    const float* wrow = comb_w + (size_t)row * (2 * H);
    float acc = 0.f;
    #pragma unroll
    for (int it = 0; it < 8; ++it) {
        int base = it * 256 + lane * 4;
        float4 wv = *reinterpret_cast<const float4*>(wrow + base);
        float4 cv = (it < 4)
            ? *reinterpret_cast<const float4*>(embed + base)
            : *reinterpret_cast<const float4*>(attnApplied + (base - H));
        acc += wv.x * cv.x + wv.y * cv.y + wv.z * cv.z + wv.w * cv.w;
    }
    acc = wave_reduce_sum(acc);
    if (lane == 0) x[row] = fmaxf(acc + comb_b[row], 0.f);
}

// ---------------- D: GRU step (h0 = 0 -> gh = b_hh). Wave per output j.
__global__ void kD_gru(const float* __restrict__ w_ih,
                       const float* __restrict__ b_ih,
                       const float* __restrict__ b_hh,
                       const float* __restrict__ x,
                       float* __restrict__ d_out) {
    int lane = threadIdx.x & 63;
    int j = blockIdx.x * 4 + (threadIdx.x >> 6); // 0..1023
    float acc0 = 0.f, acc1 = 0.f, acc2 = 0.f;
    const float* wr = w_ih + (size_t)j * H;
    const float* wz = w_ih + (size_t)(H + j) * H;
    const float* wn = w_ih + (size_t)(2 * H + j) * H;
    #pragma unroll
    for (int it = 0; it < 4; ++it) {
        int base = it * 256 + lane * 4;
        float4 xv = *reinterpret_cast<const float4*>(x + base);
        float4 a = *reinterpret_cast<const float4*>(wr + base);
        float4 b = *reinterpret_cast<const float4*>(wz + base);
        float4 c = *reinterpret_cast<const float4*>(wn + base);
        acc0 += a.x * xv.x + a.y * xv.y + a.z * xv.z + a.w * xv.w;
        acc1 += b.x * xv.x + b.y * xv.y + b.z * xv.z + b.w * xv.w;
        acc2 += c.x * xv.x + c.y * xv.y + c.z * xv.z + c.w * xv.w;
    }
    #pragma unroll
    for (int off = 32; off; off >>= 1) {
        acc0 += __shfl_xor(acc0, off);
        acc1 += __shfl_xor(acc1, off);
        acc2 += __shfl_xor(acc2, off);
    }
    if (lane == 0) {
        float gi_r = acc0 + b_ih[j];
        float gi_z = acc1 + b_ih[H + j];
        float gi_n = acc2 + b_ih[2 * H + j];
        float r = 1.f / (1.f + expf(-(gi_r + b_hh[j])));
        float z = 1.f / (1.f + expf(-(gi_z + b_hh[H + j])));
        float n = tanhf(gi_n + r * b_hh[2 * H + j]);
        float hnew = (1.f - z) * n;           // + z*h0, h0 = 0
        float outv = 1.f / (1.f + expf(-hnew));
        d_out[j] = outv;        // out
        d_out[H + j] = hnew;    // h_new
    }
}

extern "C" void kernel_launch(void* const* d_in, const int* in_sizes, int n_in,
                              void* d_out, int out_size, void* d_ws, size_t ws_size,
                              hipStream_t stream) {
    const int*   inputId     = (const int*)d_in[0];
    const float* hidden      = (const float*)d_in[1];
    const float* enc         = (const float*)d_in[2];
    const float* embed_table = (const float*)d_in[3];
    const float* attn_w      = (const float*)d_in[4];
    const float* attn_b      = (const float*)d_in[5];
    const float* comb_w      = (const float*)d_in[6];
    const float* comb_b      = (const float*)d_in[7];
    const float* w_ih        = (const float*)d_in[8];
    // d_in[9] = w_hh is dead: h0 == 0 so gh = b_hh
    const float* b_ih        = (const float*)d_in[10];
    const float* b_hh        = (const float*)d_in[11];

    float* out = (float*)d_out;   // [0:1024) out, [1024:2048) h_new, [2048:2560) attnWeights
    float* ws  = (float*)d_ws;

    float* logits      = ws;            // 512
    float* attnApplied = ws + 512;      // 1024
    float* x           = ws + 2048;     // 1024

    kA_logits       <<<128, 256, 0, stream>>>(inputId, embed_table, hidden, attn_w, attn_b, logits);
    kB_softmax_apply<<<32,  256, 0, stream>>>(logits, enc, attnApplied, out + 2048);
    kC_combine      <<<256, 256, 0, stream>>>(inputId, embed_table, attnApplied, comb_w, comb_b, x);
    kD_gru          <<<256, 256, 0, stream>>>(w_ih, b_ih, b_hh, x, out);
}